// Round 1
// baseline (347.670 us; speedup 1.0000x reference)
//
#include <hip/hip_runtime.h>
#include <hip/hip_bf16.h>

// Swin window attention, fully fused. 1 block = 1 window (B_=4096 blocks),
// 256 threads = 4 waves = 4 heads in the attention phases.
// N=49 tokens (padded to 64), DIM=128, H=4, HD=32.

typedef short bf16x8 __attribute__((ext_vector_type(8)));
typedef float f32x4  __attribute__((ext_vector_type(4)));

#define MFMA16(a, b, c) __builtin_amdgcn_mfma_f32_16x16x32_bf16((a), (b), (c), 0, 0, 0)

static __device__ __forceinline__ unsigned short f2b(float f) {
  unsigned u = __float_as_uint(f);
  u = u + 0x7FFFu + ((u >> 16) & 1u);   // RNE
  return (unsigned short)(u >> 16);
}

// ---------------- prep: weight transpose->bf16, bias+mask combine ----------------
// ws layout (bytes):
//   [0,        98304)  Wt  : bf16 [384][128], Wt[c][k] = qkv_w[k][c]
//   [98304,   131072)  Pt  : bf16 [128][128], Pt[c][k] = proj_w[k][c]
//   [131072, 1179648)  BM  : f32  [64][64][64], BM[w][q][k'] = bias[q][k]+mask[w][q][k]
//                       (k' XOR-swizzled; pad q/k>=49 -> -1e30)
__global__ void prep_kernel(const float* __restrict__ qkv_w,
                            const float* __restrict__ proj_w,
                            const float* __restrict__ bias_table,
                            const int* __restrict__ rel_index,
                            const float* __restrict__ mask,
                            unsigned short* __restrict__ Wt,
                            unsigned short* __restrict__ Pt,
                            float* __restrict__ BM) {
  int idx = blockIdx.x * 256 + threadIdx.x;
  if (idx < 384 * 128) {
    int c = idx >> 7, k = idx & 127;
    Wt[idx] = f2b(qkv_w[k * 384 + c]);
  }
  if (idx < 128 * 128) {
    int c = idx >> 7, k = idx & 127;
    Pt[idx] = f2b(proj_w[k * 128 + c]);
  }
  if (idx < 64 * 64 * 64) {
    int w = idx >> 12, r = (idx >> 6) & 63, k = idx & 63;
    float v;
    if (r < 49 && k < 49)
      v = bias_table[rel_index[r * 49 + k]] + mask[(w * 49 + r) * 49 + k];
    else
      v = -1e30f;   // key-pad -> softmax weight exactly 0; row-pad harmless
    BM[(w << 12) + (r << 6) + (k ^ ((r & 7) << 2))] = v;  // pre-swizzled
  }
}

// ---------------- fused window-attention kernel ----------------
__global__ __launch_bounds__(256, 2)
void winattn_fused(const float* __restrict__ x,
                   const float* __restrict__ qkv_b,
                   const float* __restrict__ proj_b,
                   const unsigned short* __restrict__ Wt,
                   const unsigned short* __restrict__ Pt,
                   const float* __restrict__ BM,
                   float* __restrict__ out) {
  // 64 KB LDS, 4 x 16KB regions (ushort units):
  //  R0 [0,8192)      : Xs bf16[64][128]  -> BM f32[64][64] -> Os bf16[64][128]
  //  R1 [8192,16384)  : Qs bf16[64][128]  -> Ps (heads 0,1)
  //  R2 [16384,24576) : Ks bf16[64][128]  -> Ps (heads 2,3)
  //  R3 [24576,32768) : Vt bf16[128][64]  (V transposed: Vt[h*32+d][token])
  // All row-major tiles XOR-swizzled: byte ^= (row&7)<<4.
  __shared__ unsigned short sh[32768];

  const int b    = blockIdx.x;
  const int tid  = threadIdx.x;
  const int wave = tid >> 6;
  const int lane = tid & 63;
  const int lq   = lane >> 4;   // quarter 0..3
  const int lc   = lane & 15;

  // ---- P1: x[b] (49x128 f32) -> Xs bf16, pad rows zeroed
  {
    const float4* xb = reinterpret_cast<const float4*>(x + (size_t)b * (49 * 128));
    for (int i = tid; i < 1568; i += 256) {      // 49*32 float4 units
      float4 v = xb[i];
      int row = i >> 5;
      int us  = (i & 31) ^ ((row & 7) << 1);     // swizzled 8B unit
      ushort4 w4;
      w4.x = f2b(v.x); w4.y = f2b(v.y); w4.z = f2b(v.z); w4.w = f2b(v.w);
      *reinterpret_cast<ushort4*>(&sh[row * 128 + us * 4]) = w4;
    }
    for (int i = tid; i < 480; i += 256) {       // rows 49..63 := 0
      ushort4 z; z.x = z.y = z.z = z.w = 0;
      reinterpret_cast<ushort4*>(sh)[1568 + i] = z;
    }
  }
  __syncthreads();

  // ---- P2: QKV = Xs @ Wt^T + b  -> Qs(*SCALE), Ks, Vt(transposed)
  {
    bf16x8 a[4][4];
#pragma unroll
    for (int kt = 0; kt < 4; ++kt)
#pragma unroll
      for (int mt = 0; mt < 4; ++mt) {
        int row = mt * 16 + lc;
        int col = kt * 32 + lq * 8;
        a[kt][mt] = *reinterpret_cast<const bf16x8*>(
            &sh[row * 128 + (col ^ ((row & 7) << 3))]);
      }
#pragma unroll
    for (int n6 = 0; n6 < 6; ++n6) {
      int c = (wave * 6 + n6) * 16 + lc;   // output channel 0..383
      f32x4 acc[4];
      const f32x4 vz = {0.f, 0.f, 0.f, 0.f};
#pragma unroll
      for (int mt = 0; mt < 4; ++mt) acc[mt] = vz;
      const bf16x8* wrow = reinterpret_cast<const bf16x8*>(&Wt[c * 128]);
#pragma unroll
      for (int kt = 0; kt < 4; ++kt) {
        bf16x8 bfr = wrow[kt * 4 + lq];
#pragma unroll
        for (int mt = 0; mt < 4; ++mt)
          acc[mt] = MFMA16(a[kt][mt], bfr, acc[mt]);
      }
      float bias = qkv_b[c];
#pragma unroll
      for (int mt = 0; mt < 4; ++mt)
#pragma unroll
        for (int r = 0; r < 4; ++r) {
          int t = mt * 16 + lq * 4 + r;          // token (C layout row)
          float v = acc[mt][r] + bias;
          if (c < 128) {
            sh[8192 + t * 128 + (c ^ ((t & 7) << 3))] = f2b(v * 0.17677669529663687f);
          } else if (c < 256) {
            int cc = c - 128;
            sh[16384 + t * 128 + (cc ^ ((t & 7) << 3))] = f2b(v);
          } else {
            int vc = c - 256;                    // Vt row = h*32+d = vc
            sh[24576 + vc * 64 + (t ^ ((vc & 7) << 3))] = f2b(v);
          }
        }
    }
  }
  __syncthreads();

  // ---- P3: stage BM[w] tile into R0 ; S = Q @ K^T for head = wave
  {
    const float4* bsrc = reinterpret_cast<const float4*>(BM + ((size_t)(b & 63) << 12));
    float4* bdst = reinterpret_cast<float4*>(sh);
    for (int i = tid; i < 1024; i += 256) bdst[i] = bsrc[i];
  }
  f32x4 s[4][4];
  {
    bf16x8 qf[4], kf[4];
#pragma unroll
    for (int mt = 0; mt < 4; ++mt) {
      int row = mt * 16 + lc;
      int col = wave * 32 + lq * 8;
      qf[mt] = *reinterpret_cast<const bf16x8*>(
          &sh[8192 + row * 128 + (col ^ ((row & 7) << 3))]);
    }
#pragma unroll
    for (int nt = 0; nt < 4; ++nt) {
      int row = nt * 16 + lc;
      int col = wave * 32 + lq * 8;
      kf[nt] = *reinterpret_cast<const bf16x8*>(
          &sh[16384 + row * 128 + (col ^ ((row & 7) << 3))]);
    }
    const f32x4 vz = {0.f, 0.f, 0.f, 0.f};
#pragma unroll
    for (int mt = 0; mt < 4; ++mt)
#pragma unroll
      for (int nt = 0; nt < 4; ++nt)
        s[mt][nt] = MFMA16(qf[mt], kf[nt], vz);
  }
  __syncthreads();

  // ---- P4: + (bias+mask), wave-parallel softmax, write P (unnormalized e) -> Ps
  float inv_[4][4];
  {
    const float* bml = reinterpret_cast<const float*>(sh);
#pragma unroll
    for (int mt = 0; mt < 4; ++mt)
#pragma unroll
      for (int r = 0; r < 4; ++r) {
        int q = mt * 16 + lq * 4 + r;            // query row (same for 16 lanes of quarter)
        float v[4];
#pragma unroll
        for (int nt = 0; nt < 4; ++nt) {
          int k = nt * 16 + lc;
          v[nt] = s[mt][nt][r] + bml[(q << 6) + (k ^ ((q & 7) << 2))];
        }
        float mx = fmaxf(fmaxf(v[0], v[1]), fmaxf(v[2], v[3]));
#pragma unroll
        for (int o = 1; o < 16; o <<= 1) mx = fmaxf(mx, __shfl_xor(mx, o, 64));
        float e[4], sum = 0.f;
#pragma unroll
        for (int nt = 0; nt < 4; ++nt) { e[nt] = __expf(v[nt] - mx); sum += e[nt]; }
#pragma unroll
        for (int o = 1; o < 16; o <<= 1) sum += __shfl_xor(sum, o, 64);
        inv_[mt][r] = 1.0f / sum;                // deferred normalization
#pragma unroll
        for (int nt = 0; nt < 4; ++nt) {
          int k = nt * 16 + lc;
          sh[8192 + (wave << 12) + (q << 6) + (k ^ ((q & 7) << 3))] = f2b(e[nt]);
        }
      }
  }
  __syncthreads();   // Ps visible (own wave) + all BM reads done -> R0 reusable

  // ---- P5: O = P @ V (Vt) -> Os bf16 in R0, normalized here
  {
    f32x4 o[4][2];
    const f32x4 vz = {0.f, 0.f, 0.f, 0.f};
#pragma unroll
    for (int mt = 0; mt < 4; ++mt)
#pragma unroll
      for (int nt = 0; nt < 2; ++nt) o[mt][nt] = vz;
#pragma unroll
    for (int kt = 0; kt < 2; ++kt) {
      bf16x8 pf[4];
#pragma unroll
      for (int mt = 0; mt < 4; ++mt) {
        int row = mt * 16 + lc;
        int col = kt * 32 + lq * 8;
        pf[mt] = *reinterpret_cast<const bf16x8*>(
            &sh[8192 + (wave << 12) + (row << 6) + (col ^ ((row & 7) << 3))]);
      }
#pragma unroll
      for (int nt = 0; nt < 2; ++nt) {
        int vrow = wave * 32 + nt * 16 + lc;     // h*32 + d
        int col = kt * 32 + lq * 8;              // token k
        bf16x8 vf = *reinterpret_cast<const bf16x8*>(
            &sh[24576 + vrow * 64 + (col ^ ((vrow & 7) << 3))]);
#pragma unroll
        for (int mt = 0; mt < 4; ++mt) o[mt][nt] = MFMA16(pf[mt], vf, o[mt][nt]);
      }
    }
#pragma unroll
    for (int mt = 0; mt < 4; ++mt)
#pragma unroll
      for (int nt = 0; nt < 2; ++nt)
#pragma unroll
        for (int r = 0; r < 4; ++r) {
          int t = mt * 16 + lq * 4 + r;
          int cch = wave * 32 + nt * 16 + lc;    // channel h*32+d
          sh[t * 128 + (cch ^ ((t & 7) << 3))] = f2b(o[mt][nt][r] * inv_[mt][r]);
        }
  }
  __syncthreads();

  // ---- P6: out = Os @ Pt^T + proj_b
  {
    f32x4 po[2][4];
    const f32x4 vz = {0.f, 0.f, 0.f, 0.f};
#pragma unroll
    for (int n2 = 0; n2 < 2; ++n2)
#pragma unroll
      for (int mt = 0; mt < 4; ++mt) po[n2][mt] = vz;
#pragma unroll
    for (int kt = 0; kt < 4; ++kt) {
      bf16x8 am[4];
#pragma unroll
      for (int mt = 0; mt < 4; ++mt) {
        int row = mt * 16 + lc;
        int col = kt * 32 + lq * 8;
        am[mt] = *reinterpret_cast<const bf16x8*>(
            &sh[row * 128 + (col ^ ((row & 7) << 3))]);
      }
#pragma unroll
      for (int n2 = 0; n2 < 2; ++n2) {
        int c = (wave * 2 + n2) * 16 + lc;
        bf16x8 bfr = *reinterpret_cast<const bf16x8*>(&Pt[c * 128 + kt * 32 + lq * 8]);
#pragma unroll
        for (int mt = 0; mt < 4; ++mt) po[n2][mt] = MFMA16(am[mt], bfr, po[n2][mt]);
      }
    }
    float* ob = out + (size_t)b * (49 * 128);
#pragma unroll
    for (int n2 = 0; n2 < 2; ++n2) {
      int c = (wave * 2 + n2) * 16 + lc;
      float pb = proj_b[c];
#pragma unroll
      for (int mt = 0; mt < 4; ++mt)
#pragma unroll
        for (int r = 0; r < 4; ++r) {
          int t = mt * 16 + lq * 4 + r;
          if (t < 49) ob[t * 128 + c] = po[n2][mt][r] + pb;
        }
    }
  }
}

extern "C" void kernel_launch(void* const* d_in, const int* in_sizes, int n_in,
                              void* d_out, int out_size, void* d_ws, size_t ws_size,
                              hipStream_t stream) {
  const float* x         = (const float*)d_in[0];
  const float* mask      = (const float*)d_in[1];
  const float* qkv_w     = (const float*)d_in[2];
  const float* qkv_b     = (const float*)d_in[3];
  const float* proj_w    = (const float*)d_in[4];
  const float* proj_b    = (const float*)d_in[5];
  const float* bias_tab  = (const float*)d_in[6];
  const int*   rel_index = (const int*)d_in[7];
  float* out = (float*)d_out;

  unsigned short* Wt = (unsigned short*)d_ws;                       // 384*128 bf16
  unsigned short* Pt = (unsigned short*)((char*)d_ws + 98304);      // 128*128 bf16
  float*          BM = (float*)((char*)d_ws + 131072);              // 64*64*64 f32

  hipLaunchKernelGGL(prep_kernel, dim3(1024), dim3(256), 0, stream,
                     qkv_w, proj_w, bias_tab, rel_index, mask, Wt, Pt, BM);
  hipLaunchKernelGGL(winattn_fused, dim3(4096), dim3(256), 0, stream,
                     x, qkv_b, proj_b, Wt, Pt, BM, out);
}

// Round 2
// 296.435 us; speedup vs baseline: 1.1728x; 1.1728x over previous
//
#include <hip/hip_runtime.h>
#include <hip/hip_bf16.h>

// Swin window attention, fully fused, all-swapped-MFMA layout.
// 1 block = 1 window (4096 blocks), 256 threads = 4 waves = 4 heads.
// N=49 tokens (padded to 64), DIM=128, H=4, HD=32.

typedef short bf16x8 __attribute__((ext_vector_type(8)));
typedef float f32x4  __attribute__((ext_vector_type(4)));

#define MFMA16(a, b, c) __builtin_amdgcn_mfma_f32_16x16x32_bf16((a), (b), (c), 0, 0, 0)

static __device__ __forceinline__ unsigned short f2b(float f) {
  unsigned u = __float_as_uint(f);
  u = u + 0x7FFFu + ((u >> 16) & 1u);   // RNE
  return (unsigned short)(u >> 16);
}

// ---------------- prep ----------------
// ws layout (bytes):
//   [0,      98304)   Wt  : bf16 [384][128], Wt[c][k] = qkv_w[k][c]
//   [98304, 131072)   Pt  : bf16 [128][128], Pt[c][k] = proj_w[k][c]
//   [131072,1179648)  BM2 : f32  [64][mt(4)][nt(4)][lane(64)][r(4)]
//                      = bias[q][k]+mask[w][q][k], q=mt*16+lc, k=nt*16+lq*4+r
//                      (pad q/k>=49 -> -1e30); fragment-order => coalesced float4
__global__ void prep_kernel(const float* __restrict__ qkv_w,
                            const float* __restrict__ proj_w,
                            const float* __restrict__ bias_table,
                            const int* __restrict__ rel_index,
                            const float* __restrict__ mask,
                            unsigned short* __restrict__ Wt,
                            unsigned short* __restrict__ Pt,
                            float* __restrict__ BM2) {
  int idx = blockIdx.x * 256 + threadIdx.x;
  if (idx < 384 * 128) {
    int c = idx >> 7, k = idx & 127;
    Wt[idx] = f2b(qkv_w[k * 384 + c]);
  }
  if (idx < 128 * 128) {
    int c = idx >> 7, k = idx & 127;
    Pt[idx] = f2b(proj_w[k * 128 + c]);
  }
  if (idx < 64 * 4096) {
    int w = idx >> 12, rem = idx & 4095;
    int mt = rem >> 10, nt = (rem >> 8) & 3, ln = (rem >> 2) & 63, r = rem & 3;
    int lq = ln >> 4, lc = ln & 15;
    int q = mt * 16 + lc, k = nt * 16 + lq * 4 + r;
    float v = -1e30f;
    if (q < 49 && k < 49)
      v = bias_table[rel_index[q * 49 + k]] + mask[(w * 49 + q) * 49 + k];
    BM2[idx] = v;
  }
}

// ---------------- fused kernel ----------------
__global__ __launch_bounds__(256, 3)
void winattn_fused(const float* __restrict__ x,
                   const float* __restrict__ qkv_b,
                   const float* __restrict__ proj_b,
                   const unsigned short* __restrict__ Wt,
                   const unsigned short* __restrict__ Pt,
                   const float* __restrict__ BM2,
                   float* __restrict__ out) {
  // 48 KB LDS (ushort units):
  //  R0 [0,8192)      : Vt bf16[128][64]   (Vt[h*32+d][t])
  //  R1 [8192,16384)  : Q bf16[64][128] -> P heads 0,1 -> Os bf16[64][128]
  //  R2 [16384,24576) : K bf16[64][128] -> P heads 2,3
  // Row-major tiles swizzled: ushort_idx ^= (row&7)<<3  (16B granule).
  __shared__ unsigned short sh[24576];

  const int b    = blockIdx.x;
  const int tid  = threadIdx.x;
  const int wave = tid >> 6;
  const int lane = tid & 63;
  const int lq   = lane >> 4;
  const int lc   = lane & 15;

  // ---- load X fragments straight from global (rows t=mt*16+lc, k=kt*32+lq*8)
  bf16x8 xf[4][4];   // [kt][mt]
  {
    const float* xb = x + (size_t)b * (49 * 128);
#pragma unroll
    for (int mt = 0; mt < 4; ++mt) {
      int t = mt * 16 + lc;
      bool valid = (t < 49);
#pragma unroll
      for (int kt = 0; kt < 4; ++kt) {
        bf16x8 r;
        if (valid) {
          const float* p = xb + t * 128 + kt * 32 + lq * 8;
          float4 a0 = *reinterpret_cast<const float4*>(p);
          float4 a1 = *reinterpret_cast<const float4*>(p + 4);
          r[0] = (short)f2b(a0.x); r[1] = (short)f2b(a0.y);
          r[2] = (short)f2b(a0.z); r[3] = (short)f2b(a0.w);
          r[4] = (short)f2b(a1.x); r[5] = (short)f2b(a1.y);
          r[6] = (short)f2b(a1.z); r[7] = (short)f2b(a1.w);
        } else {
          r = (bf16x8)0;
        }
        xf[kt][mt] = r;
      }
    }
  }

  const f32x4 vzero = {0.f, 0.f, 0.f, 0.f};

  // ---- P2: QKV. Q/K swapped-orientation (vector writes of 4 consecutive
  //          channels); V normal orientation (vector writes of 4 consecutive
  //          tokens into Vt). Columns wave-interleaved for balance.
  {
    // Q/K: cols {wave, wave+4, wave+8, wave+12}
#pragma unroll
    for (int i = 0; i < 4; ++i) {
      int col = wave + i * 4;              // <16
      bf16x8 wtf[4];
#pragma unroll
      for (int kt = 0; kt < 4; ++kt)
        wtf[kt] = *reinterpret_cast<const bf16x8*>(
            &Wt[(col * 16 + lc) * 128 + kt * 32 + lq * 8]);
      f32x4 acc[4];
#pragma unroll
      for (int mt = 0; mt < 4; ++mt) acc[mt] = vzero;
#pragma unroll
      for (int kt = 0; kt < 4; ++kt)
#pragma unroll
        for (int mt = 0; mt < 4; ++mt)
          acc[mt] = MFMA16(wtf[kt], xf[kt][mt], acc[mt]);  // C[c][t]
      float4 b4 = *reinterpret_cast<const float4*>(&qkv_b[col * 16 + lq * 4]);
      bool isQ = (i < 2);
      float scale = isQ ? 0.17677669529663687f : 1.0f;
      int base = isQ ? 8192 : 16384;
      int cp = (col & 7) * 16 + lq * 4;    // channel within the 128-wide tile
#pragma unroll
      for (int mt = 0; mt < 4; ++mt) {
        int t = mt * 16 + lc;
        ushort4 w4;
        w4.x = f2b((acc[mt][0] + b4.x) * scale);
        w4.y = f2b((acc[mt][1] + b4.y) * scale);
        w4.z = f2b((acc[mt][2] + b4.z) * scale);
        w4.w = f2b((acc[mt][3] + b4.w) * scale);
        *reinterpret_cast<ushort4*>(&sh[base + t * 128 + (cp ^ ((t & 7) << 3))]) = w4;
      }
    }
    // V: cols {wave+16, wave+20}
#pragma unroll
    for (int i = 0; i < 2; ++i) {
      int col = 16 + wave + i * 4;
      bf16x8 wtf[4];
#pragma unroll
      for (int kt = 0; kt < 4; ++kt)
        wtf[kt] = *reinterpret_cast<const bf16x8*>(
            &Wt[(col * 16 + lc) * 128 + kt * 32 + lq * 8]);
      f32x4 acc[4];
#pragma unroll
      for (int mt = 0; mt < 4; ++mt) acc[mt] = vzero;
#pragma unroll
      for (int kt = 0; kt < 4; ++kt)
#pragma unroll
        for (int mt = 0; mt < 4; ++mt)
          acc[mt] = MFMA16(xf[kt][mt], wtf[kt], acc[mt]);  // C[t][c]
      int vc = (col - 16) * 16 + lc;       // V channel = Vt row
      float bias = qkv_b[256 + vc];
#pragma unroll
      for (int mt = 0; mt < 4; ++mt) {
        int t0 = mt * 16 + lq * 4;
        ushort4 w4;
        w4.x = f2b(acc[mt][0] + bias);
        w4.y = f2b(acc[mt][1] + bias);
        w4.z = f2b(acc[mt][2] + bias);
        w4.w = f2b(acc[mt][3] + bias);
        *reinterpret_cast<ushort4*>(&sh[vc * 64 + (t0 ^ ((vc & 7) << 3))]) = w4;
      }
    }
  }
  __syncthreads();

  // ---- P3: S^T = K·Q (swapped). head = wave. Lane holds k=nt*16+lq*4+r, q=mt*16+lc.
  f32x4 s[4][4];   // [nt(k)][mt(q)]
  {
    bf16x8 qf[4], kf[4];
    int d0 = wave * 32 + lq * 8;
#pragma unroll
    for (int mt = 0; mt < 4; ++mt) {
      int t = mt * 16 + lc;
      qf[mt] = *reinterpret_cast<const bf16x8*>(
          &sh[8192 + t * 128 + (d0 ^ ((t & 7) << 3))]);
    }
#pragma unroll
    for (int nt = 0; nt < 4; ++nt) {
      int t = nt * 16 + lc;
      kf[nt] = *reinterpret_cast<const bf16x8*>(
          &sh[16384 + t * 128 + (d0 ^ ((t & 7) << 3))]);
    }
#pragma unroll
    for (int nt = 0; nt < 4; ++nt)
#pragma unroll
      for (int mt = 0; mt < 4; ++mt)
        s[nt][mt] = MFMA16(kf[nt], qf[mt], vzero);
  }
  __syncthreads();   // all Q/K reads done -> R1/R2 reusable for P

  // ---- P4: softmax (BM2 from L2), P (unnormalized) -> LDS, b64 writes
  float inv_[4];
  {
    const float* bm = BM2 + ((size_t)(b & 63) << 12);
    const int pbase = 8192 + wave * 4096;   // P tile for this head: [64q][64k]
#pragma unroll
    for (int mt = 0; mt < 4; ++mt) {
      float4 bmv[4];
#pragma unroll
      for (int nt = 0; nt < 4; ++nt)
        bmv[nt] = *reinterpret_cast<const float4*>(&bm[((mt * 4 + nt) * 64 + lane) * 4]);
      float v[4][4];
#pragma unroll
      for (int nt = 0; nt < 4; ++nt) {
        v[nt][0] = s[nt][mt][0] + bmv[nt].x;
        v[nt][1] = s[nt][mt][1] + bmv[nt].y;
        v[nt][2] = s[nt][mt][2] + bmv[nt].z;
        v[nt][3] = s[nt][mt][3] + bmv[nt].w;
      }
      float mx = v[0][0];
#pragma unroll
      for (int nt = 0; nt < 4; ++nt)
#pragma unroll
        for (int r = 0; r < 4; ++r) mx = fmaxf(mx, v[nt][r]);
      mx = fmaxf(mx, __shfl_xor(mx, 16, 64));
      mx = fmaxf(mx, __shfl_xor(mx, 32, 64));
      float e[4][4], sum = 0.f;
#pragma unroll
      for (int nt = 0; nt < 4; ++nt)
#pragma unroll
        for (int r = 0; r < 4; ++r) { e[nt][r] = __expf(v[nt][r] - mx); sum += e[nt][r]; }
      sum += __shfl_xor(sum, 16, 64);
      sum += __shfl_xor(sum, 32, 64);
      inv_[mt] = 1.0f / sum;
      int q = mt * 16 + lc;
#pragma unroll
      for (int nt = 0; nt < 4; ++nt) {
        int k0 = nt * 16 + lq * 4;
        ushort4 w4;
        w4.x = f2b(e[nt][0]); w4.y = f2b(e[nt][1]);
        w4.z = f2b(e[nt][2]); w4.w = f2b(e[nt][3]);
        *reinterpret_cast<ushort4*>(&sh[pbase + q * 64 + (k0 ^ ((q & 7) << 3))]) = w4;
      }
    }
  }
  // no barrier: each wave reads only its own P tile (same-wave LDS RAW)

  // ---- P5: O^T = Vt·P (swapped). Lane: d rows 4-consec, q col = lc.
  f32x4 oacc[2][4];  // [db][qb]
  {
#pragma unroll
    for (int db = 0; db < 2; ++db)
#pragma unroll
      for (int qb = 0; qb < 4; ++qb) oacc[db][qb] = vzero;
    const int pbase = 8192 + wave * 4096;
#pragma unroll
    for (int kt = 0; kt < 2; ++kt) {
      int k0 = kt * 32 + lq * 8;
      bf16x8 vtf[2];
#pragma unroll
      for (int db = 0; db < 2; ++db) {
        int vr = wave * 32 + db * 16 + lc;
        vtf[db] = *reinterpret_cast<const bf16x8*>(
            &sh[vr * 64 + (k0 ^ ((vr & 7) << 3))]);
      }
      bf16x8 pf[4];
#pragma unroll
      for (int qb = 0; qb < 4; ++qb) {
        int q = qb * 16 + lc;
        pf[qb] = *reinterpret_cast<const bf16x8*>(
            &sh[pbase + q * 64 + (k0 ^ ((q & 7) << 3))]);
      }
#pragma unroll
      for (int db = 0; db < 2; ++db)
#pragma unroll
        for (int qb = 0; qb < 4; ++qb)
          oacc[db][qb] = MFMA16(vtf[db], pf[qb], oacc[db][qb]);
    }
  }
  __syncthreads();   // all P/Vt reads done -> R1 reusable for Os
  {
#pragma unroll
    for (int db = 0; db < 2; ++db)
#pragma unroll
      for (int qb = 0; qb < 4; ++qb) {
        int t = qb * 16 + lc;
        int d0 = wave * 32 + db * 16 + lq * 4;
        float iv = inv_[qb];
        ushort4 w4;
        w4.x = f2b(oacc[db][qb][0] * iv);
        w4.y = f2b(oacc[db][qb][1] * iv);
        w4.z = f2b(oacc[db][qb][2] * iv);
        w4.w = f2b(oacc[db][qb][3] * iv);
        *reinterpret_cast<ushort4*>(&sh[8192 + t * 128 + (d0 ^ ((t & 7) << 3))]) = w4;
      }
  }
  __syncthreads();

  // ---- P6: out^T = Pt·Os (swapped). Lane: c_out 4-consec, t col = lc. float4 stores.
  {
    float* ob = out + (size_t)b * (49 * 128);
#pragma unroll
    for (int i = 0; i < 2; ++i) {
      int cb = wave * 2 + i;
      bf16x8 ptf[4];
#pragma unroll
      for (int kt = 0; kt < 4; ++kt)
        ptf[kt] = *reinterpret_cast<const bf16x8*>(
            &Pt[(cb * 16 + lc) * 128 + kt * 32 + lq * 8]);
      f32x4 acc[4];
#pragma unroll
      for (int tb = 0; tb < 4; ++tb) acc[tb] = vzero;
#pragma unroll
      for (int kt = 0; kt < 4; ++kt) {
        int d0 = kt * 32 + lq * 8;
#pragma unroll
        for (int tb = 0; tb < 4; ++tb) {
          int t = tb * 16 + lc;
          bf16x8 osf = *reinterpret_cast<const bf16x8*>(
              &sh[8192 + t * 128 + (d0 ^ ((t & 7) << 3))]);
          acc[tb] = MFMA16(ptf[kt], osf, acc[tb]);
        }
      }
      float4 pb4 = *reinterpret_cast<const float4*>(&proj_b[cb * 16 + lq * 4]);
#pragma unroll
      for (int tb = 0; tb < 4; ++tb) {
        int t = tb * 16 + lc;
        if (t < 49) {
          float4 o4;
          o4.x = acc[tb][0] + pb4.x;
          o4.y = acc[tb][1] + pb4.y;
          o4.z = acc[tb][2] + pb4.z;
          o4.w = acc[tb][3] + pb4.w;
          *reinterpret_cast<float4*>(&ob[t * 128 + cb * 16 + lq * 4]) = o4;
        }
      }
    }
  }
}

extern "C" void kernel_launch(void* const* d_in, const int* in_sizes, int n_in,
                              void* d_out, int out_size, void* d_ws, size_t ws_size,
                              hipStream_t stream) {
  const float* x         = (const float*)d_in[0];
  const float* mask      = (const float*)d_in[1];
  const float* qkv_w     = (const float*)d_in[2];
  const float* qkv_b     = (const float*)d_in[3];
  const float* proj_w    = (const float*)d_in[4];
  const float* proj_b    = (const float*)d_in[5];
  const float* bias_tab  = (const float*)d_in[6];
  const int*   rel_index = (const int*)d_in[7];
  float* out = (float*)d_out;

  unsigned short* Wt = (unsigned short*)d_ws;                       // 384*128 bf16
  unsigned short* Pt = (unsigned short*)((char*)d_ws + 98304);      // 128*128 bf16
  float*          BM2 = (float*)((char*)d_ws + 131072);             // 64*4096 f32

  hipLaunchKernelGGL(prep_kernel, dim3(1024), dim3(256), 0, stream,
                     qkv_w, proj_w, bias_tab, rel_index, mask, Wt, Pt, BM2);
  hipLaunchKernelGGL(winattn_fused, dim3(4096), dim3(256), 0, stream,
                     x, qkv_b, proj_b, Wt, Pt, BM2, out);
}